// Round 7
// baseline (421.692 us; speedup 1.0000x reference)
//
#include <hip/hip_runtime.h>

typedef unsigned short u16;
typedef short bf16x8 __attribute__((ext_vector_type(8)));
typedef float f32x4  __attribute__((ext_vector_type(4)));

#define NA 22       /* agents per graph */
#define FIN 32      /* input feature dim */
#define XS_STR 520  /* padded LDS row stride (elements): 1040B, bank-conflict-free */
#define ALT_STR 24  /* transposed-alpha row stride (floats): 96B, float4-aligned */

/* d_ws layout (u16 elements): W1s [0,16384) W2s [16384,278528) W3s [278528,344064) */
#define W1_OFF 0
#define W2_OFF 16384
#define W3_OFF 278528
#define WS_TOTAL 344064

__device__ float b2f(u16 u) {
    return __uint_as_float(((unsigned int)u) << 16);
}

__device__ u16 f2b(float f) {
    unsigned int x = __float_as_uint(f);
    x = (x + 0x7fffu + ((x >> 16) & 1u)) >> 16;  /* round-nearest-even */
    return (u16)x;
}

/* Swizzle fp32 W [K][N] -> bf16 MFMA B-fragment layout:
   frag(kt,nt) is 512 u16: lane l (0..63), elem j (0..7) holds
   W[kt*32 + (l>>4)*8 + j][nt*16 + (l&15)]. */
__global__ void swizzle_kernel(const float* W1, const float* W2, const float* W3, u16* ws)
{
    int t = blockIdx.x * 256 + threadIdx.x;
    const float* W;
    int NT, N, loc;
    if (t < W2_OFF)         { W = W1; NT = 32; N = 512; loc = t; }
    else if (t < W3_OFF)    { W = W2; NT = 32; N = 512; loc = t - W2_OFF; }
    else if (t < WS_TOTAL)  { W = W3; NT = 8;  N = 128; loc = t - W3_OFF; }
    else { return; }
    int tile = loc >> 9;
    int r    = loc & 511;
    int lane = r >> 3;
    int j    = r & 7;
    int kt = tile / NT;
    int nt = tile - kt * NT;
    int k = kt * 32 + (lane >> 4) * 8 + j;
    int n = nt * 16 + (lane & 15);
    ws[t] = f2b(W[k * N + n]);
}

/* GEMM h = x*W via mfma_f32_16x16x32_bf16, with the s/d attention dot
   products fused into the epilogue (computed from fp32 accumulators,
   16-lane shuffle reduction). For H=4 wave w owns exactly head w's 128
   columns -> sv[w*NA+row] is the complete dot; for H=1 each wave writes a
   partial over its 32 columns, summed in the softmax phase. */
__device__ __forceinline__ void mfma_gemm_att(
    const u16* xs, u16* hs, const u16* Wsw,
    const float* avs, const float* avd,
    int K, int COLS, float* sv, float* dv)
{
    int NT  = COLS >> 4;
    int KT  = K >> 5;
    int NTW = NT >> 2;                 /* n-tiles per wave: 8, 8, 2 */
    int tid  = threadIdx.x;
    int wave = tid >> 6, lane = tid & 63;
    int quad = lane >> 4, lm = lane & 15;

    int r1 = 16 + lm;
    if (r1 >= NA) { r1 = lm; }         /* safe dummy row for pad lanes */
    const u16* a0base = xs + lm * XS_STR;
    const u16* a1base = xs + r1 * XS_STR;

    f32x4 acc[2][8];
    for (int mt = 0; mt < 2; ++mt) {
        for (int n = 0; n < NTW; ++n) {
            f32x4 z = {0.f, 0.f, 0.f, 0.f};
            acc[mt][n] = z;
        }
    }
    for (int kt = 0; kt < KT; ++kt) {
        bf16x8 a0 = *(const bf16x8*)(a0base + kt * 32 + quad * 8);
        bf16x8 a1 = *(const bf16x8*)(a1base + kt * 32 + quad * 8);
        #pragma unroll
        for (int n = 0; n < NTW; ++n) {
            int nt = wave * NTW + n;
            bf16x8 b = *(const bf16x8*)(Wsw + ((kt * NT + nt) << 9) + (lane << 3));
            acc[0][n] = __builtin_amdgcn_mfma_f32_16x16x32_bf16(a0, b, acc[0][n], 0, 0, 0);
            acc[1][n] = __builtin_amdgcn_mfma_f32_16x16x32_bf16(a1, b, acc[1][n], 0, 0, 0);
        }
    }

    /* per-lane slices of the attention vectors for this wave's columns */
    float asv[8], adv[8];
    for (int n = 0; n < NTW; ++n) {
        int col = (wave * NTW + n) * 16 + lm;   /* == hh*C + c for both H */
        asv[n] = avs[col];
        adv[n] = avd[col];
    }

    /* epilogue: store h (bf16) + fused s/d partials */
    for (int mt = 0; mt < 2; ++mt) {
        for (int r = 0; r < 4; ++r) {
            int row = mt * 16 + quad * 4 + r;
            float ps = 0.0f, pd = 0.0f;
            #pragma unroll
            for (int n = 0; n < NTW; ++n) {
                float v = acc[mt][n][r];
                ps += v * asv[n];
                pd += v * adv[n];
            }
            ps += __shfl_xor(ps, 1);  ps += __shfl_xor(ps, 2);
            ps += __shfl_xor(ps, 4);  ps += __shfl_xor(ps, 8);
            pd += __shfl_xor(pd, 1);  pd += __shfl_xor(pd, 2);
            pd += __shfl_xor(pd, 4);  pd += __shfl_xor(pd, 8);
            if (row < NA) {
                #pragma unroll
                for (int n = 0; n < NTW; ++n) {
                    hs[row * XS_STR + (wave * NTW + n) * 16 + lm] = f2b(acc[mt][n][r]);
                }
                if (lm == 0) {
                    sv[wave * NA + row] = ps;
                    dv[wave * NA + row] = pd;
                }
            }
        }
    }
}

__device__ __forceinline__ void gat_layer(const u16* Wsw, const float* avs, const float* avd,
                                          const float* bias, int K, int H, int C,
                                          u16* xs, u16* hs, float* sv, float* dv, float* al_t)
{
    int COLS = H * C;
    int tid = threadIdx.x;

    mfma_gemm_att(xs, hs, Wsw, avs, avd, K, COLS, sv, dv);
    __syncthreads();

    /* softmax over sources j, leaky-relu(0.2) on logits; writes al_t[j][i] */
    if (tid < H * NA) {
        int hh = tid / NA;
        int ii = tid - hh * NA;
        float di;
        if (H == 1) { di = dv[ii] + dv[NA + ii] + dv[2 * NA + ii] + dv[3 * NA + ii]; }
        else        { di = dv[tid]; }
        float lg[NA];
        float mx = -1.0e30f;
        float ss = 0.0f;
        for (int j = 0; j < NA; ++j) {
            float sj;
            if (H == 1) { sj = sv[j] + sv[NA + j] + sv[2 * NA + j] + sv[3 * NA + j]; }
            else        { sj = sv[hh * NA + j]; }
            float l = di + sj;
            if (l < 0.0f) { l = l * 0.2f; }
            lg[j] = l;
            if (l > mx) { mx = l; }
        }
        for (int j = 0; j < NA; ++j) {
            float e = expf(lg[j] - mx);
            lg[j] = e;
            ss += e;
        }
        float inv = 1.0f / ss;
        for (int j = 0; j < NA; ++j) {
            al_t[(hh * NA + j) * ALT_STR + ii] = lg[j] * inv;
        }
    }
    __syncthreads();

    /* aggregate: xs[i][c] = relu(bias[c] + sum_j al[h][i][j]*hs[j][c]);
       2 cols/thread; alpha read as broadcast float4 rows of al_t */
    if (tid * 2 < COLS) {
        int c0 = tid * 2;
        int hh = c0 >> 7;                      /* C == 128 in all layers */
        float acc0[NA], acc1[NA];
        for (int i = 0; i < NA; ++i) { acc0[i] = 0.0f; acc1[i] = 0.0f; }
        for (int j = 0; j < NA; ++j) {
            unsigned int hx = *(const unsigned int*)(hs + j * XS_STR + c0);
            float h0 = __uint_as_float(hx << 16);
            float h1 = __uint_as_float(hx & 0xffff0000u);
            const f32x4* ap = (const f32x4*)(al_t + (hh * NA + j) * ALT_STR);
            f32x4 A[6];
            #pragma unroll
            for (int u = 0; u < 6; ++u) { A[u] = ap[u]; }
            #pragma unroll
            for (int u = 0; u < 6; ++u) {
                #pragma unroll
                for (int e = 0; e < 4; ++e) {
                    int i = u * 4 + e;
                    if (i < NA) {
                        float a = A[u][e];
                        acc0[i] += a * h0;
                        acc1[i] += a * h1;
                    }
                }
            }
        }
        float bv0 = bias[c0];
        float bv1 = bias[c0 + 1];
        for (int i = 0; i < NA; ++i) {
            float v0 = acc0[i] + bv0; if (v0 < 0.0f) { v0 = 0.0f; }
            float v1 = acc1[i] + bv1; if (v1 < 0.0f) { v1 = 0.0f; }
            unsigned int packed = (unsigned int)f2b(v0) | (((unsigned int)f2b(v1)) << 16);
            *(unsigned int*)(xs + i * XS_STR + c0) = packed;
        }
    }
    __syncthreads();
}

__global__ void pressgnn_kernel(const float* feats, const u16* ws,
                                const float* as1, const float* ad1, const float* b1,
                                const float* as2, const float* ad2, const float* b2,
                                const float* as3, const float* ad3, const float* b3,
                                const float* Wc, const float* bc,
                                float* out)
{
    __shared__ u16  xs[NA * XS_STR];          /* 22880 B */
    __shared__ u16  hs[NA * XS_STR];          /* 22880 B */
    __shared__ float sv[4 * NA];
    __shared__ float dv[4 * NA];
    __shared__ float al_t[4 * NA * ALT_STR];  /* 8448 B; reused as pool scratch */

    int g = blockIdx.x;
    int tid = threadIdx.x;

    /* load this graph's features: [NA][FIN] fp32 -> bf16 LDS (padded stride) */
    for (int i = tid; i < NA * FIN; i += 256) {
        int row = i >> 5;
        int col = i & 31;
        xs[row * XS_STR + col] = f2b(feats[g * NA * FIN + i]);
    }
    __syncthreads();

    gat_layer(ws + W1_OFF, as1, ad1, b1, 32,  4, 128, xs, hs, sv, dv, al_t);
    gat_layer(ws + W2_OFF, as2, ad2, b2, 512, 4, 128, xs, hs, sv, dv, al_t);
    gat_layer(ws + W3_OFF, as3, ad3, b3, 512, 1, 128, xs, hs, sv, dv, al_t);
    /* xs now holds [NA][128] relu'd (H=1: head-mean is identity) */

    /* global mean pool over agents + final linear 128->1 (al_t reused) */
    if (tid < 128) {
        float s = 0.0f;
        for (int a = 0; a < NA; ++a) { s += b2f(xs[a * XS_STR + tid]); }
        al_t[tid] = (s / 22.0f) * Wc[tid];
    }
    __syncthreads();
    if (tid == 0) {
        float t = 0.0f;
        for (int c = 0; c < 128; ++c) { t += al_t[c]; }
        out[g] = t + bc[0];
    }
}

extern "C" void kernel_launch(void* const* d_in, const int* in_sizes, int n_in,
                              void* d_out, int out_size, void* d_ws, size_t ws_size,
                              hipStream_t stream) {
    const float* feats = (const float*)d_in[0];
    const float* W1  = (const float*)d_in[1];
    const float* as1 = (const float*)d_in[2];
    const float* ad1 = (const float*)d_in[3];
    const float* b1  = (const float*)d_in[4];
    const float* W2  = (const float*)d_in[5];
    const float* as2 = (const float*)d_in[6];
    const float* ad2 = (const float*)d_in[7];
    const float* b2  = (const float*)d_in[8];
    const float* W3  = (const float*)d_in[9];
    const float* as3 = (const float*)d_in[10];
    const float* ad3 = (const float*)d_in[11];
    const float* b3  = (const float*)d_in[12];
    const float* Wc  = (const float*)d_in[13];
    const float* bc  = (const float*)d_in[14];
    float* out = (float*)d_out;
    u16* ws = (u16*)d_ws;

    /* per-launch weight swizzle into d_ws (d_ws is re-poisoned before every call) */
    swizzle_kernel<<<dim3((WS_TOTAL + 255) / 256), dim3(256), 0, stream>>>(W1, W2, W3, ws);

    /* one block per graph; graph count == output element count (B*T = 4096) */
    pressgnn_kernel<<<dim3(out_size), dim3(256), 0, stream>>>(
        feats, ws,
        as1, ad1, b1,
        as2, ad2, b2,
        as3, ad3, b3,
        Wc, bc, out);
}

// Round 8
// 359.578 us; speedup vs baseline: 1.1727x; 1.1727x over previous
//
#include <hip/hip_runtime.h>

typedef unsigned short u16;
typedef short bf16x8 __attribute__((ext_vector_type(8)));
typedef float f32x4  __attribute__((ext_vector_type(4)));

#define NA 22       /* agents per graph */
#define FIN 32      /* input feature dim */
#define XS_STR 520  /* padded LDS row stride (elements): 1040B, bank-conflict-free */
#define ALT_STR 24  /* transposed-alpha row stride (floats): 96B, float4-aligned */

/* d_ws layout (u16 elements): W1s [0,16384) W2s [16384,278528) W3s [278528,344064) */
#define W1_OFF 0
#define W2_OFF 16384
#define W3_OFF 278528
#define WS_TOTAL 344064

__device__ float b2f(u16 u) {
    return __uint_as_float(((unsigned int)u) << 16);
}

__device__ u16 f2b(float f) {
    unsigned int x = __float_as_uint(f);
    x = (x + 0x7fffu + ((x >> 16) & 1u)) >> 16;  /* round-nearest-even */
    return (u16)x;
}

/* Swizzle fp32 W [K][N] -> bf16 MFMA B-fragment layout; 8 outputs per thread.
   frag(kt,nt), lane l, elem j holds W[kt*32 + (l>>4)*8 + j][nt*16 + (l&15)].
   Thread t owns outputs [t*8, t*8+8) = one (lane) slot of one fragment:
   reads are 16-consecutive-col segments (coalesced in 64B chunks), write is
   one aligned 16B store. */
__global__ void swizzle_kernel(const float* W1, const float* W2, const float* W3, u16* ws)
{
    int base = (blockIdx.x * 256 + threadIdx.x) * 8;
    const float* W;
    int NT, N, loc;
    if (base < W2_OFF)         { W = W1; NT = 32; N = 512; loc = base; }
    else if (base < W3_OFF)    { W = W2; NT = 32; N = 512; loc = base - W2_OFF; }
    else if (base < WS_TOTAL)  { W = W3; NT = 8;  N = 128; loc = base - W3_OFF; }
    else { return; }
    int tile = loc >> 9;
    int lane = (loc & 511) >> 3;
    int kt = tile / NT;
    int nt = tile - kt * NT;
    int k0 = kt * 32 + (lane >> 4) * 8;
    int n  = nt * 16 + (lane & 15);
    bf16x8 v;
    #pragma unroll
    for (int j = 0; j < 8; ++j) { v[j] = (short)f2b(W[(k0 + j) * N + n]); }
    *(bf16x8*)(ws + base) = v;
}

/* hs[a][col] = sum_f xs[a][f] * W[f][col] via mfma_f32_16x16x32_bf16.
   Compile-time KT/NT/NTW -> full unroll + manual next-kt prefetch so the
   B-fragment L2 loads pipeline instead of serializing at ~200cyc each.
   M=22 in two m-tiles; 2nd tile's pad lanes read a dummy valid row (their
   D-rows are never stored). */
template<int KT, int NT, int NTW>
__device__ __forceinline__ void mfma_gemm(const u16* xs, u16* hs, const u16* Wsw)
{
    int tid  = threadIdx.x;
    int wave = tid >> 6, lane = tid & 63;
    int quad = lane >> 4, lm = lane & 15;

    int r1 = 16 + lm;
    if (r1 >= NA) { r1 = lm; }
    const u16* a0base = xs + lm * XS_STR;
    const u16* a1base = xs + r1 * XS_STR;
    const u16* wbase  = Wsw + ((wave * NTW) << 9) + (lane << 3);

    f32x4 acc0[NTW], acc1[NTW];
    #pragma unroll
    for (int n = 0; n < NTW; ++n) {
        f32x4 z = {0.f, 0.f, 0.f, 0.f};
        acc0[n] = z; acc1[n] = z;
    }

    bf16x8 bcur[NTW];
    #pragma unroll
    for (int n = 0; n < NTW; ++n) { bcur[n] = *(const bf16x8*)(wbase + (n << 9)); }
    bf16x8 a0 = *(const bf16x8*)(a0base + quad * 8);
    bf16x8 a1 = *(const bf16x8*)(a1base + quad * 8);

    #pragma unroll
    for (int kt = 0; kt < KT; ++kt) {
        bf16x8 bnxt[NTW];
        bf16x8 a0n, a1n;
        if (kt + 1 < KT) {
            const u16* wn = wbase + (((kt + 1) * NT) << 9);
            #pragma unroll
            for (int n = 0; n < NTW; ++n) { bnxt[n] = *(const bf16x8*)(wn + (n << 9)); }
            a0n = *(const bf16x8*)(a0base + (kt + 1) * 32 + quad * 8);
            a1n = *(const bf16x8*)(a1base + (kt + 1) * 32 + quad * 8);
        }
        #pragma unroll
        for (int n = 0; n < NTW; ++n) {
            acc0[n] = __builtin_amdgcn_mfma_f32_16x16x32_bf16(a0, bcur[n], acc0[n], 0, 0, 0);
            acc1[n] = __builtin_amdgcn_mfma_f32_16x16x32_bf16(a1, bcur[n], acc1[n], 0, 0, 0);
        }
        if (kt + 1 < KT) {
            #pragma unroll
            for (int n = 0; n < NTW; ++n) { bcur[n] = bnxt[n]; }
            a0 = a0n; a1 = a1n;
        }
    }

    /* D layout: row = mt*16 + quad*4 + r, col = nt*16 + lm */
    #pragma unroll
    for (int n = 0; n < NTW; ++n) {
        int nt = wave * NTW + n;
        #pragma unroll
        for (int r = 0; r < 4; ++r) {
            int row0 = quad * 4 + r;
            hs[row0 * XS_STR + nt * 16 + lm] = f2b(acc0[n][r]);
            int row1 = 16 + quad * 4 + r;
            if (row1 < NA) { hs[row1 * XS_STR + nt * 16 + lm] = f2b(acc1[n][r]); }
        }
    }
}

template<int KT, int NT, int NTW, int H>
__device__ __forceinline__ void gat_layer(const u16* Wsw, const float* avs, const float* avd,
                                          const float* bias,
                                          u16* xs, u16* hs, float* sv, float* dv, float* al_t)
{
    const int COLS = NT * 16;
    int tid = threadIdx.x;

    mfma_gemm<KT, NT, NTW>(xs, hs, Wsw);
    __syncthreads();

    /* attention coefficients: sv[h*NA+a] = h_a . a_src, dv likewise.
       2*H*NA independent threads, vectorized b64/float4 reads. */
    if (tid < 2 * H * NA) {
        int which = tid / (H * NA);
        int pair = tid - which * (H * NA);
        int hh = pair / NA;
        int aa = pair - hh * NA;
        const float* av = which ? avd : avs;
        float sum = 0.0f;
        for (int c = 0; c < 128; c += 4) {
            uint2 hx = *(const uint2*)(hs + aa * XS_STR + hh * 128 + c);
            f32x4 a  = *(const f32x4*)(av + hh * 128 + c);
            sum += __uint_as_float(hx.x << 16)          * a[0]
                 + __uint_as_float(hx.x & 0xffff0000u)  * a[1]
                 + __uint_as_float(hx.y << 16)          * a[2]
                 + __uint_as_float(hx.y & 0xffff0000u)  * a[3];
        }
        if (which) { dv[pair] = sum; } else { sv[pair] = sum; }
    }
    __syncthreads();

    /* softmax over sources j, leaky-relu(0.2) on logits; writes al_t[j][i] */
    if (tid < H * NA) {
        int hh = tid / NA;
        int ii = tid - hh * NA;
        float di = dv[tid];
        float lg[NA];
        float mx = -1.0e30f;
        float ss = 0.0f;
        for (int j = 0; j < NA; ++j) {
            float l = di + sv[hh * NA + j];
            if (l < 0.0f) { l = l * 0.2f; }
            lg[j] = l;
            if (l > mx) { mx = l; }
        }
        for (int j = 0; j < NA; ++j) {
            float e = expf(lg[j] - mx);
            lg[j] = e;
            ss += e;
        }
        float inv = 1.0f / ss;
        for (int j = 0; j < NA; ++j) {
            al_t[(hh * NA + j) * ALT_STR + ii] = lg[j] * inv;
        }
    }
    __syncthreads();

    /* aggregate: xs[i][c] = relu(bias[c] + sum_j al[h][i][j]*hs[j][c]);
       2 cols/thread; alpha read as broadcast float4 rows of al_t */
    if (tid * 2 < COLS) {
        int c0 = tid * 2;
        int hh = c0 >> 7;                      /* C == 128 in all layers */
        float acc0[NA], acc1[NA];
        for (int i = 0; i < NA; ++i) { acc0[i] = 0.0f; acc1[i] = 0.0f; }
        for (int j = 0; j < NA; ++j) {
            unsigned int hx = *(const unsigned int*)(hs + j * XS_STR + c0);
            float h0 = __uint_as_float(hx << 16);
            float h1 = __uint_as_float(hx & 0xffff0000u);
            const f32x4* ap = (const f32x4*)(al_t + (hh * NA + j) * ALT_STR);
            f32x4 A[6];
            #pragma unroll
            for (int u = 0; u < 6; ++u) { A[u] = ap[u]; }
            #pragma unroll
            for (int u = 0; u < 6; ++u) {
                #pragma unroll
                for (int e = 0; e < 4; ++e) {
                    int i = u * 4 + e;
                    if (i < NA) {
                        float a = A[u][e];
                        acc0[i] += a * h0;
                        acc1[i] += a * h1;
                    }
                }
            }
        }
        float bv0 = bias[c0];
        float bv1 = bias[c0 + 1];
        for (int i = 0; i < NA; ++i) {
            float v0 = acc0[i] + bv0; if (v0 < 0.0f) { v0 = 0.0f; }
            float v1 = acc1[i] + bv1; if (v1 < 0.0f) { v1 = 0.0f; }
            unsigned int packed = (unsigned int)f2b(v0) | (((unsigned int)f2b(v1)) << 16);
            *(unsigned int*)(xs + i * XS_STR + c0) = packed;
        }
    }
    __syncthreads();
}

__global__ void __launch_bounds__(256, 2)
pressgnn_kernel(const float* feats, const u16* ws,
                const float* as1, const float* ad1, const float* b1,
                const float* as2, const float* ad2, const float* b2,
                const float* as3, const float* ad3, const float* b3,
                const float* Wc, const float* bc,
                float* out)
{
    __shared__ u16  xs[NA * XS_STR];          /* 22880 B */
    __shared__ u16  hs[NA * XS_STR];          /* 22880 B */
    __shared__ float sv[4 * NA];
    __shared__ float dv[4 * NA];
    __shared__ float al_t[4 * NA * ALT_STR];  /* 8448 B; reused as pool scratch */

    int g = blockIdx.x;
    int tid = threadIdx.x;

    /* load this graph's features: [NA][FIN] fp32 -> bf16 LDS (padded stride) */
    for (int i = tid; i < NA * FIN; i += 256) {
        int row = i >> 5;
        int col = i & 31;
        xs[row * XS_STR + col] = f2b(feats[g * NA * FIN + i]);
    }
    __syncthreads();

    gat_layer<1,  32, 8, 4>(ws + W1_OFF, as1, ad1, b1, xs, hs, sv, dv, al_t);
    gat_layer<16, 32, 8, 4>(ws + W2_OFF, as2, ad2, b2, xs, hs, sv, dv, al_t);
    gat_layer<16, 8,  2, 1>(ws + W3_OFF, as3, ad3, b3, xs, hs, sv, dv, al_t);
    /* xs now holds [NA][128] relu'd (H=1: head-mean is identity) */

    /* global mean pool over agents + final linear 128->1 (al_t reused) */
    if (tid < 128) {
        float s = 0.0f;
        for (int a = 0; a < NA; ++a) { s += b2f(xs[a * XS_STR + tid]); }
        al_t[tid] = (s / 22.0f) * Wc[tid];
    }
    __syncthreads();
    if (tid == 0) {
        float t = 0.0f;
        for (int c = 0; c < 128; ++c) { t += al_t[c]; }
        out[g] = t + bc[0];
    }
}

extern "C" void kernel_launch(void* const* d_in, const int* in_sizes, int n_in,
                              void* d_out, int out_size, void* d_ws, size_t ws_size,
                              hipStream_t stream) {
    const float* feats = (const float*)d_in[0];
    const float* W1  = (const float*)d_in[1];
    const float* as1 = (const float*)d_in[2];
    const float* ad1 = (const float*)d_in[3];
    const float* b1  = (const float*)d_in[4];
    const float* W2  = (const float*)d_in[5];
    const float* as2 = (const float*)d_in[6];
    const float* ad2 = (const float*)d_in[7];
    const float* b2  = (const float*)d_in[8];
    const float* W3  = (const float*)d_in[9];
    const float* as3 = (const float*)d_in[10];
    const float* ad3 = (const float*)d_in[11];
    const float* b3  = (const float*)d_in[12];
    const float* Wc  = (const float*)d_in[13];
    const float* bc  = (const float*)d_in[14];
    float* out = (float*)d_out;
    u16* ws = (u16*)d_ws;

    /* per-launch weight swizzle into d_ws */
    swizzle_kernel<<<dim3(WS_TOTAL / 8 / 256), dim3(256), 0, stream>>>(W1, W2, W3, ws);

    /* one block per graph; graph count == output element count (B*T = 4096) */
    pressgnn_kernel<<<dim3(out_size), dim3(256), 0, stream>>>(
        feats, ws,
        as1, ad1, b1,
        as2, ad2, b2,
        as3, ad3, b3,
        Wc, bc, out);
}

// Round 9
// 341.213 us; speedup vs baseline: 1.2359x; 1.0538x over previous
//
#include <hip/hip_runtime.h>

typedef unsigned short u16;
typedef short bf16x8 __attribute__((ext_vector_type(8)));
typedef float f32x4  __attribute__((ext_vector_type(4)));
typedef float v2f    __attribute__((ext_vector_type(2)));

#define NA 22       /* agents per graph */
#define FIN 32      /* input feature dim */
#define XS_STR 520  /* padded LDS row stride (elements): 1040B, bank-conflict-free */
#define ALT_STR 24  /* transposed-alpha row stride (floats): 96B, float4-aligned */

/* d_ws layout (u16 elements): W1s [0,16384) W2s [16384,278528) W3s [278528,344064) */
#define W1_OFF 0
#define W2_OFF 16384
#define W3_OFF 278528
#define WS_TOTAL 344064

__device__ float b2f(u16 u) {
    return __uint_as_float(((unsigned int)u) << 16);
}

__device__ u16 f2b(float f) {
    unsigned int x = __float_as_uint(f);
    x = (x + 0x7fffu + ((x >> 16) & 1u)) >> 16;  /* round-nearest-even */
    return (u16)x;
}

/* Swizzle fp32 W [K][N] -> bf16 MFMA B-fragment layout; 8 outputs per thread.
   frag(kt,nt), lane l, elem j holds W[kt*32 + (l>>4)*8 + j][nt*16 + (l&15)]. */
__global__ void swizzle_kernel(const float* W1, const float* W2, const float* W3, u16* ws)
{
    int base = (blockIdx.x * 256 + threadIdx.x) * 8;
    const float* W;
    int NT, N, loc;
    if (base < W2_OFF)         { W = W1; NT = 32; N = 512; loc = base; }
    else if (base < W3_OFF)    { W = W2; NT = 32; N = 512; loc = base - W2_OFF; }
    else if (base < WS_TOTAL)  { W = W3; NT = 8;  N = 128; loc = base - W3_OFF; }
    else { return; }
    int tile = loc >> 9;
    int lane = (loc & 511) >> 3;
    int kt = tile / NT;
    int nt = tile - kt * NT;
    int k0 = kt * 32 + (lane >> 4) * 8;
    int n  = nt * 16 + (lane & 15);
    bf16x8 v;
    #pragma unroll
    for (int j = 0; j < 8; ++j) { v[j] = (short)f2b(W[(k0 + j) * N + n]); }
    *(bf16x8*)(ws + base) = v;
}

/* hs[a][col] = sum_f xs[a][f] * W[f][col] via mfma_f32_16x16x32_bf16.
   Double-buffered by unrolled parity index (no register rotate). */
template<int KT, int NT, int NTW>
__device__ __forceinline__ void mfma_gemm(const u16* xs, u16* hs, const u16* Wsw)
{
    int tid  = threadIdx.x;
    int wave = tid >> 6, lane = tid & 63;
    int quad = lane >> 4, lm = lane & 15;

    int r1 = 16 + lm;
    if (r1 >= NA) { r1 = lm; }
    const u16* a0base = xs + lm * XS_STR + quad * 8;
    const u16* a1base = xs + r1 * XS_STR + quad * 8;
    const u16* wbase  = Wsw + ((wave * NTW) << 9) + (lane << 3);

    f32x4 acc0[NTW], acc1[NTW];
    #pragma unroll
    for (int n = 0; n < NTW; ++n) {
        f32x4 z = {0.f, 0.f, 0.f, 0.f};
        acc0[n] = z; acc1[n] = z;
    }

    bf16x8 bbuf[2][NTW];
    bf16x8 abuf0[2], abuf1[2];
    #pragma unroll
    for (int n = 0; n < NTW; ++n) { bbuf[0][n] = *(const bf16x8*)(wbase + (n << 9)); }
    abuf0[0] = *(const bf16x8*)(a0base);
    abuf1[0] = *(const bf16x8*)(a1base);

    #pragma unroll
    for (int kt = 0; kt < KT; ++kt) {
        const int cur = kt & 1;
        const int nxt = cur ^ 1;
        if (kt + 1 < KT) {
            const u16* wn = wbase + (((kt + 1) * NT) << 9);
            #pragma unroll
            for (int n = 0; n < NTW; ++n) { bbuf[nxt][n] = *(const bf16x8*)(wn + (n << 9)); }
            abuf0[nxt] = *(const bf16x8*)(a0base + (kt + 1) * 32);
            abuf1[nxt] = *(const bf16x8*)(a1base + (kt + 1) * 32);
        }
        #pragma unroll
        for (int n = 0; n < NTW; ++n) {
            acc0[n] = __builtin_amdgcn_mfma_f32_16x16x32_bf16(abuf0[cur], bbuf[cur][n], acc0[n], 0, 0, 0);
            acc1[n] = __builtin_amdgcn_mfma_f32_16x16x32_bf16(abuf1[cur], bbuf[cur][n], acc1[n], 0, 0, 0);
        }
    }

    /* D layout: row = mt*16 + quad*4 + r, col = nt*16 + lm */
    #pragma unroll
    for (int n = 0; n < NTW; ++n) {
        int nt = wave * NTW + n;
        #pragma unroll
        for (int r = 0; r < 4; ++r) {
            int row0 = quad * 4 + r;
            hs[row0 * XS_STR + nt * 16 + lm] = f2b(acc0[n][r]);
            int row1 = 16 + quad * 4 + r;
            if (row1 < NA) { hs[row1 * XS_STR + nt * 16 + lm] = f2b(acc1[n][r]); }
        }
    }
}

template<int KT, int NT, int NTW, int H>
__device__ __forceinline__ void gat_layer(const u16* Wsw, const float* avs, const float* avd,
                                          const float* bias,
                                          u16* xs, u16* hs, float* sv, float* dv, float* al_t)
{
    const int COLS = NT * 16;
    int tid = threadIdx.x;

    mfma_gemm<KT, NT, NTW>(xs, hs, Wsw);
    __syncthreads();

    /* attention coefficients: sv[h*NA+a] = h_a . a_src, dv likewise */
    if (tid < 2 * H * NA) {
        int which = tid / (H * NA);
        int pair = tid - which * (H * NA);
        int hh = pair / NA;
        int aa = pair - hh * NA;
        const float* av = which ? avd : avs;
        v2f sum2 = {0.f, 0.f};
        #pragma unroll 4
        for (int c = 0; c < 128; c += 4) {
            uint2 hx = *(const uint2*)(hs + aa * XS_STR + hh * 128 + c);
            f32x4 a  = *(const f32x4*)(av + hh * 128 + c);
            v2f h01, h23, a01, a23;
            h01[0] = __uint_as_float(hx.x << 16);
            h01[1] = __uint_as_float(hx.x & 0xffff0000u);
            h23[0] = __uint_as_float(hx.y << 16);
            h23[1] = __uint_as_float(hx.y & 0xffff0000u);
            a01[0] = a[0]; a01[1] = a[1];
            a23[0] = a[2]; a23[1] = a[3];
            sum2 = h01 * a01 + sum2;
            sum2 = h23 * a23 + sum2;
        }
        float sum = sum2[0] + sum2[1];
        if (which) { dv[pair] = sum; } else { sv[pair] = sum; }
    }
    __syncthreads();

    /* softmax over sources j, leaky-relu(0.2) on logits; writes al_t[j][i] */
    if (tid < H * NA) {
        int hh = tid / NA;
        int ii = tid - hh * NA;
        float di = dv[tid];
        float lg[NA];
        float mx = -1.0e30f;
        float ss = 0.0f;
        #pragma unroll
        for (int j = 0; j < NA; ++j) {
            float l = di + sv[hh * NA + j];
            l = fmaxf(l, 0.2f * l);            /* leaky relu, slope 0.2 */
            lg[j] = l;
            mx = fmaxf(mx, l);
        }
        #pragma unroll
        for (int j = 0; j < NA; ++j) {
            float e = __expf(lg[j] - mx);
            lg[j] = e;
            ss += e;
        }
        float inv = 1.0f / ss;
        #pragma unroll
        for (int j = 0; j < NA; ++j) {
            al_t[(hh * NA + j) * ALT_STR + ii] = lg[j] * inv;
        }
    }
    __syncthreads();

    /* aggregate: xs[i][c] = relu(bias[c] + sum_j al[h][i][j]*hs[j][c]);
       2 cols/thread accumulated as float2 (v_pk_fma_f32) */
    if (tid * 2 < COLS) {
        int c0 = tid * 2;
        int hh = c0 >> 7;                      /* C == 128 in all layers */
        v2f acc[NA];
        #pragma unroll
        for (int i = 0; i < NA; ++i) { v2f z = {0.f, 0.f}; acc[i] = z; }
        for (int j = 0; j < NA; ++j) {
            unsigned int hx = *(const unsigned int*)(hs + j * XS_STR + c0);
            v2f h2;
            h2[0] = __uint_as_float(hx << 16);
            h2[1] = __uint_as_float(hx & 0xffff0000u);
            const f32x4* ap = (const f32x4*)(al_t + (hh * NA + j) * ALT_STR);
            f32x4 A[6];
            #pragma unroll
            for (int u = 0; u < 6; ++u) { A[u] = ap[u]; }
            #pragma unroll
            for (int u = 0; u < 6; ++u) {
                #pragma unroll
                for (int e = 0; e < 4; ++e) {
                    int i = u * 4 + e;
                    if (i < NA) {
                        v2f av2 = {A[u][e], A[u][e]};
                        acc[i] = h2 * av2 + acc[i];
                    }
                }
            }
        }
        float bv0 = bias[c0];
        float bv1 = bias[c0 + 1];
        #pragma unroll
        for (int i = 0; i < NA; ++i) {
            float v0 = fmaxf(acc[i][0] + bv0, 0.0f);
            float v1 = fmaxf(acc[i][1] + bv1, 0.0f);
            unsigned int packed = (unsigned int)f2b(v0) | (((unsigned int)f2b(v1)) << 16);
            *(unsigned int*)(xs + i * XS_STR + c0) = packed;
        }
    }
    __syncthreads();
}

__global__ void __launch_bounds__(256, 2)
pressgnn_kernel(const float* feats, const u16* ws,
                const float* as1, const float* ad1, const float* b1,
                const float* as2, const float* ad2, const float* b2,
                const float* as3, const float* ad3, const float* b3,
                const float* Wc, const float* bc,
                float* out)
{
    __shared__ u16  xs[NA * XS_STR];          /* 22880 B */
    __shared__ u16  hs[NA * XS_STR];          /* 22880 B */
    __shared__ float sv[4 * NA];
    __shared__ float dv[4 * NA];
    __shared__ float al_t[4 * NA * ALT_STR];  /* 8448 B; reused as pool scratch */

    int g = blockIdx.x;
    int tid = threadIdx.x;

    /* load this graph's features: [NA][FIN] fp32 -> bf16 LDS (padded stride) */
    for (int i = tid; i < NA * FIN; i += 256) {
        int row = i >> 5;
        int col = i & 31;
        xs[row * XS_STR + col] = f2b(feats[g * NA * FIN + i]);
    }
    __syncthreads();

    gat_layer<1,  32, 8, 4>(ws + W1_OFF, as1, ad1, b1, xs, hs, sv, dv, al_t);
    gat_layer<16, 32, 8, 4>(ws + W2_OFF, as2, ad2, b2, xs, hs, sv, dv, al_t);
    gat_layer<16, 8,  2, 1>(ws + W3_OFF, as3, ad3, b3, xs, hs, sv, dv, al_t);
    /* xs now holds [NA][128] relu'd (H=1: head-mean is identity) */

    /* global mean pool over agents + final linear 128->1 (al_t reused) */
    if (tid < 128) {
        float s = 0.0f;
        #pragma unroll
        for (int a = 0; a < NA; ++a) { s += b2f(xs[a * XS_STR + tid]); }
        al_t[tid] = (s / 22.0f) * Wc[tid];
    }
    __syncthreads();
    if (tid == 0) {
        float t = 0.0f;
        for (int c = 0; c < 128; ++c) { t += al_t[c]; }
        out[g] = t + bc[0];
    }
}

extern "C" void kernel_launch(void* const* d_in, const int* in_sizes, int n_in,
                              void* d_out, int out_size, void* d_ws, size_t ws_size,
                              hipStream_t stream) {
    const float* feats = (const float*)d_in[0];
    const float* W1  = (const float*)d_in[1];
    const float* as1 = (const float*)d_in[2];
    const float* ad1 = (const float*)d_in[3];
    const float* b1  = (const float*)d_in[4];
    const float* W2  = (const float*)d_in[5];
    const float* as2 = (const float*)d_in[6];
    const float* ad2 = (const float*)d_in[7];
    const float* b2  = (const float*)d_in[8];
    const float* W3  = (const float*)d_in[9];
    const float* as3 = (const float*)d_in[10];
    const float* ad3 = (const float*)d_in[11];
    const float* b3  = (const float*)d_in[12];
    const float* Wc  = (const float*)d_in[13];
    const float* bc  = (const float*)d_in[14];
    float* out = (float*)d_out;
    u16* ws = (u16*)d_ws;

    /* per-launch weight swizzle into d_ws */
    swizzle_kernel<<<dim3(WS_TOTAL / 8 / 256), dim3(256), 0, stream>>>(W1, W2, W3, ws);

    /* one block per graph; graph count == output element count (B*T = 4096) */
    pressgnn_kernel<<<dim3(out_size), dim3(256), 0, stream>>>(
        feats, ws,
        as1, ad1, b1,
        as2, ad2, b2,
        as3, ad3, b3,
        Wc, bc, out);
}

// Round 10
// 258.958 us; speedup vs baseline: 1.6284x; 1.3176x over previous
//
#include <hip/hip_runtime.h>

typedef unsigned short u16;
typedef unsigned long long u64;
typedef short bf16x8 __attribute__((ext_vector_type(8)));
typedef float f32x4  __attribute__((ext_vector_type(4)));

#define NA 22       /* agents per graph */
#define FIN 32      /* input feature dim */
#define XS_STR 520  /* xs LDS row stride (u16): 1040B, conflict-free A-frag reads */
#define HS_STR 24   /* hs_t (transposed h) row stride (u16): [col][agent 0..23] */
#define AL_STR 24   /* alpha row stride (u16): [dst i][src j 0..23], j 22,23 zeroed */

/* d_ws layout (u16): main B-frags then fused-attention (Wav) frags */
#define W1_OFF 0          /* 32 frags   */
#define W2_OFF 16384      /* 512 frags  */
#define W3_OFF 278528     /* 128 frags  */
#define E1_OFF 344064     /* 1 frag     */
#define E2_OFF 344576     /* 16 frags   */
#define E3_OFF 352768     /* 16 frags   */
#define WS_TOTAL 360960

__device__ float b2f(u16 u) {
    return __uint_as_float(((unsigned int)u) << 16);
}

__device__ u16 f2b(float f) {
    unsigned int x = __float_as_uint(f);
    x = (x + 0x7fffu + ((x >> 16) & 1u)) >> 16;  /* round-nearest-even */
    return (u16)x;
}

/* W [K][N] fp32 -> bf16 B-frag layout, scatter form (coalesced reads):
   element (k,n) -> frag(kt=k/32, nt=n/16), lane=(k%32/8)*16 + n%16, j=k%8 */
__global__ void swizzle_kernel(const float* W1, const float* W2, const float* W3, u16* ws)
{
    int t = blockIdx.x * 256 + threadIdx.x;
    const float* W; int NT, nshift, base, loc;
    if (t < W2_OFF)      { W = W1; NT = 32; nshift = 9; base = W1_OFF; loc = t; }
    else if (t < W3_OFF) { W = W2; NT = 32; nshift = 9; base = W2_OFF; loc = t - W2_OFF; }
    else if (t < E1_OFF) { W = W3; NT = 8;  nshift = 7; base = W3_OFF; loc = t - W3_OFF; }
    else { return; }
    int k = loc >> nshift;
    int n = loc & ((1 << nshift) - 1);
    u16 v = f2b(W[loc]);
    int kt = k >> 5, quad = (k & 31) >> 3, j = k & 7;
    int nt = n >> 4, lm = n & 15;
    int lane = (quad << 4) | lm;
    ws[base + (((kt * NT + nt) << 9) | (lane << 3) | j)] = v;
}

/* Wav[f][col] = sum_c W[f][h*128+c]*av[h][c]: fused s/d columns, frag layout.
   cols 0..H-1 = src heads, H..2H-1 = dst heads, rest zero. */
__global__ void wav_kernel(const float* W1, const float* as1, const float* ad1,
                           const float* W2, const float* as2, const float* ad2,
                           const float* W3, const float* as3, const float* ad3,
                           u16* ws)
{
    int t = blockIdx.x * 256 + threadIdx.x;   /* 16896 total */
    const float* W; const float* asp; const float* adp;
    int H, N, base, loc;
    if (t < 512)        { W = W1; asp = as1; adp = ad1; H = 4; N = 512; base = E1_OFF; loc = t; }
    else if (t < 8704)  { W = W2; asp = as2; adp = ad2; H = 4; N = 512; base = E2_OFF; loc = t - 512; }
    else if (t < 16896) { W = W3; asp = as3; adp = ad3; H = 1; N = 128; base = E3_OFF; loc = t - 8704; }
    else { return; }
    int kt = loc >> 9, r = loc & 511;
    int lane = r >> 3, j = r & 7;
    int quad = lane >> 4, lm = lane & 15;
    u16 outv = 0;
    if (lm < 2 * H) {
        int h = (H == 4) ? (lm & 3) : 0;
        int which = (H == 4) ? (lm >> 2) : lm;
        const float* av = which ? adp : asp;
        int k = kt * 32 + quad * 8 + j;
        float s = 0.f;
        for (int c = 0; c < 128; ++c) { s += W[k * N + h * 128 + c] * av[h * 128 + c]; }
        outv = f2b(s);
    }
    ws[base + (kt << 9) + (lane << 3) + j] = outv;
}

__device__ __forceinline__ u64 pack4(f32x4 v) {
    return (u64)f2b(v[0]) | ((u64)f2b(v[1]) << 16)
         | ((u64)f2b(v[2]) << 32) | ((u64)f2b(v[3]) << 48);
}

template<int KT, int NT, int NTW, int H>
__device__ __forceinline__ void gat_layer(
    const u16* Wsw, const u16* Wext, const float* bias,
    u16* xs, u16* hs_t, float* sv, float* dv, u16* al)
{
    int tid  = threadIdx.x;
    int wave = tid >> 6, lane = tid & 63;
    int quad = lane >> 4, lm = lane & 15;

    /* ---------- GEMM h = x@W (+ fused s/d columns on wave 0) ---------- */
    {
        int r1 = 16 + lm; if (r1 >= NA) { r1 = lm; }   /* dummy valid row */
        const u16* a0base = xs + lm * XS_STR + quad * 8;
        const u16* a1base = xs + r1 * XS_STR + quad * 8;
        const u16* wbase  = Wsw + ((wave * NTW) << 9) + (lane << 3);
        const u16* ebase  = Wext + (lane << 3);

        f32x4 acc0[NTW], acc1[NTW], accE0, accE1;
        f32x4 z4 = {0.f, 0.f, 0.f, 0.f};
        #pragma unroll
        for (int n = 0; n < NTW; ++n) { acc0[n] = z4; acc1[n] = z4; }
        accE0 = z4; accE1 = z4;

        bf16x8 bbuf[2][NTW], ebuf[2], ab0[2], ab1[2];
        #pragma unroll
        for (int n = 0; n < NTW; ++n) { bbuf[0][n] = *(const bf16x8*)(wbase + (n << 9)); }
        if (wave == 0) { ebuf[0] = *(const bf16x8*)(ebase); }
        ab0[0] = *(const bf16x8*)(a0base);
        ab1[0] = *(const bf16x8*)(a1base);

        #pragma unroll
        for (int kt = 0; kt < KT; ++kt) {
            const int cur = kt & 1;
            const int nxt = cur ^ 1;
            if (kt + 1 < KT) {
                const u16* wn = wbase + (((kt + 1) * NT) << 9);
                #pragma unroll
                for (int n = 0; n < NTW; ++n) { bbuf[nxt][n] = *(const bf16x8*)(wn + (n << 9)); }
                if (wave == 0) { ebuf[nxt] = *(const bf16x8*)(ebase + ((kt + 1) << 9)); }
                ab0[nxt] = *(const bf16x8*)(a0base + (kt + 1) * 32);
                ab1[nxt] = *(const bf16x8*)(a1base + (kt + 1) * 32);
            }
            #pragma unroll
            for (int n = 0; n < NTW; ++n) {
                acc0[n] = __builtin_amdgcn_mfma_f32_16x16x32_bf16(ab0[cur], bbuf[cur][n], acc0[n], 0, 0, 0);
                acc1[n] = __builtin_amdgcn_mfma_f32_16x16x32_bf16(ab1[cur], bbuf[cur][n], acc1[n], 0, 0, 0);
            }
            if (wave == 0) {
                accE0 = __builtin_amdgcn_mfma_f32_16x16x32_bf16(ab0[cur], ebuf[cur], accE0, 0, 0, 0);
                accE1 = __builtin_amdgcn_mfma_f32_16x16x32_bf16(ab1[cur], ebuf[cur], accE1, 0, 0, 0);
            }
        }

        /* epilogue: h -> hs_t[col][agent] as packed b64 stores */
        #pragma unroll
        for (int n = 0; n < NTW; ++n) {
            u16* colp = hs_t + ((wave * NTW + n) * 16 + lm) * HS_STR;
            *(u64*)(colp + quad * 4) = pack4(acc0[n]);
            if (quad < 2) {                          /* agents 16..23 (22,23 pad) */
                *(u64*)(colp + 16 + quad * 4) = pack4(acc1[n]);
            }
        }
        /* fused attention coefficients (fp32, exact) */
        if (wave == 0) {
            #pragma unroll
            for (int r = 0; r < 4; ++r) {
                int row0 = quad * 4 + r;
                if (lm < H)            { sv[lm * NA + row0] = accE0[r]; }
                else if (lm < 2 * H)   { dv[(lm - H) * NA + row0] = accE0[r]; }
                int row1 = 16 + quad * 4 + r;
                if (row1 < NA) {
                    if (lm < H)          { sv[lm * NA + row1] = accE1[r]; }
                    else if (lm < 2 * H) { dv[(lm - H) * NA + row1] = accE1[r]; }
                }
            }
        }
    }
    __syncthreads();

    /* ---------- softmax -> alpha (bf16, A-frag row layout) ---------- */
    if (tid < H * NA) {
        int hh = tid / NA;
        int ii = tid - hh * NA;
        float di = dv[tid];
        float lg[NA];
        float mx = -1.0e30f, ss = 0.0f;
        #pragma unroll
        for (int j = 0; j < NA; ++j) {
            float l = di + sv[hh * NA + j];
            l = fmaxf(l, 0.2f * l);                  /* leaky relu 0.2 */
            lg[j] = l;
            mx = fmaxf(mx, l);
        }
        #pragma unroll
        for (int j = 0; j < NA; ++j) {
            float e = __expf(lg[j] - mx);
            lg[j] = e;
            ss += e;
        }
        float inv = 1.0f / ss;
        u16* arow = al + (hh * NA + ii) * AL_STR;
        #pragma unroll
        for (int j = 0; j < NA; ++j) { arow[j] = f2b(lg[j] * inv); }
        arow[22] = 0; arow[23] = 0;                  /* zero K-pad */
    }
    __syncthreads();

    /* ---------- aggregate out = alpha @ h via MFMA; +bias, relu -> xs ---------- */
    {
        int head = (H == 4) ? wave : 0;
        const u16* albase = al + head * NA * AL_STR;
        bf16x8 zb = {0, 0, 0, 0, 0, 0, 0, 0};
        int r1 = 16 + lm; if (r1 >= NA) { r1 = lm; }
        bf16x8 pa0 = (quad < 3) ? *(const bf16x8*)(albase + lm * AL_STR + quad * 8) : zb;
        bf16x8 pa1 = (quad < 3) ? *(const bf16x8*)(albase + r1 * AL_STR + quad * 8) : zb;

        f32x4 agg0[NTW], agg1[NTW];
        f32x4 z4 = {0.f, 0.f, 0.f, 0.f};
        float bv[NTW];
        #pragma unroll
        for (int n = 0; n < NTW; ++n) {
            int col = (wave * NTW + n) * 16 + lm;
            bv[n] = bias[col];
            bf16x8 pb = *(const bf16x8*)(hs_t + col * HS_STR + quad * 8);
            agg0[n] = __builtin_amdgcn_mfma_f32_16x16x32_bf16(pa0, pb, z4, 0, 0, 0);
            agg1[n] = __builtin_amdgcn_mfma_f32_16x16x32_bf16(pa1, pb, z4, 0, 0, 0);
        }
        #pragma unroll
        for (int n = 0; n < NTW; ++n) {
            int col = (wave * NTW + n) * 16 + lm;
            #pragma unroll
            for (int r = 0; r < 4; ++r) {
                int row0 = quad * 4 + r;
                xs[row0 * XS_STR + col] = f2b(fmaxf(agg0[n][r] + bv[n], 0.0f));
                int row1 = 16 + quad * 4 + r;
                if (row1 < NA) {
                    xs[row1 * XS_STR + col] = f2b(fmaxf(agg1[n][r] + bv[n], 0.0f));
                }
            }
        }
    }
    __syncthreads();
}

__global__ void __launch_bounds__(256, 2)
pressgnn_kernel(const float* feats, const u16* ws,
                const float* b1, const float* b2, const float* b3,
                const float* Wc, const float* bc,
                float* out)
{
    __shared__ __align__(16) u16 xs[NA * XS_STR];        /* 22880 B */
    __shared__ __align__(16) u16 hs_t[512 * HS_STR + 8]; /* 24592 B */
    __shared__ __align__(16) u16 al[4 * NA * AL_STR];    /*  4224 B */
    __shared__ float sv[4 * NA];
    __shared__ float dv[4 * NA];
    __shared__ float pool[128];

    int g = blockIdx.x;
    int tid = threadIdx.x;

    /* load this graph's features: [NA][FIN] fp32 -> bf16 LDS */
    for (int i = tid; i < NA * FIN; i += 256) {
        int row = i >> 5;
        int col = i & 31;
        xs[row * XS_STR + col] = f2b(feats[g * NA * FIN + i]);
    }
    __syncthreads();

    gat_layer<1,  32, 8, 4>(ws + W1_OFF, ws + E1_OFF, b1, xs, hs_t, sv, dv, al);
    gat_layer<16, 32, 8, 4>(ws + W2_OFF, ws + E2_OFF, b2, xs, hs_t, sv, dv, al);
    gat_layer<16, 8,  2, 1>(ws + W3_OFF, ws + E3_OFF, b3, xs, hs_t, sv, dv, al);
    /* xs now holds [NA][128] relu'd (H=1: head-mean is identity) */

    /* global mean pool over agents + final linear 128->1 */
    if (tid < 128) {
        float s = 0.0f;
        #pragma unroll
        for (int a = 0; a < NA; ++a) { s += b2f(xs[a * XS_STR + tid]); }
        pool[tid] = (s / 22.0f) * Wc[tid];
    }
    __syncthreads();
    if (tid == 0) {
        float t = 0.0f;
        for (int c = 0; c < 128; ++c) { t += pool[c]; }
        out[g] = t + bc[0];
    }
}

extern "C" void kernel_launch(void* const* d_in, const int* in_sizes, int n_in,
                              void* d_out, int out_size, void* d_ws, size_t ws_size,
                              hipStream_t stream) {
    const float* feats = (const float*)d_in[0];
    const float* W1  = (const float*)d_in[1];
    const float* as1 = (const float*)d_in[2];
    const float* ad1 = (const float*)d_in[3];
    const float* b1  = (const float*)d_in[4];
    const float* W2  = (const float*)d_in[5];
    const float* as2 = (const float*)d_in[6];
    const float* ad2 = (const float*)d_in[7];
    const float* b2  = (const float*)d_in[8];
    const float* W3  = (const float*)d_in[9];
    const float* as3 = (const float*)d_in[10];
    const float* ad3 = (const float*)d_in[11];
    const float* b3  = (const float*)d_in[12];
    const float* Wc  = (const float*)d_in[13];
    const float* bc  = (const float*)d_in[14];
    float* out = (float*)d_out;
    u16* ws = (u16*)d_ws;

    /* per-launch weight prep into d_ws (re-poisoned before every call) */
    swizzle_kernel<<<dim3(1344), dim3(256), 0, stream>>>(W1, W2, W3, ws);
    wav_kernel<<<dim3(66), dim3(256), 0, stream>>>(W1, as1, ad1, W2, as2, ad2,
                                                   W3, as3, ad3, ws);

    /* one block per graph; graph count == output element count (B*T = 4096) */
    pressgnn_kernel<<<dim3(out_size), dim3(256), 0, stream>>>(
        feats, ws, b1, b2, b3, Wc, bc, out);
}